// Round 1
// baseline (2223.221 us; speedup 1.0000x reference)
//
#include <hip/hip_runtime.h>

// Problem constants: T=2048, B=256, F=64, H=256, O=1
#define T_STEPS 2048
#define BATCH   256
#define FEAT    64
#define HID     256
#define KAUG    320   // FEAT + HID
#define NTHR    1024  // 16 waves/block, 4 waves/EU, 1 block/CU (grid 256)
#define NW      16
#define KSL     8     // k-slices (mapped to lane bits 0..2)
#define KCH     40    // KAUG / KSL floats per lane-slice
#define NC      10    // KCH / 4 float4 chunks

typedef float f32x4 __attribute__((ext_vector_type(4)));

// fast tanh: tanh(z) = 1 - 2/(exp(2z)+1). Saturates correctly at +/-inf.
__device__ __forceinline__ float fast_tanh(float z) {
    float e = __expf(2.0f * z);
    return 1.0f - 2.0f * __builtin_amdgcn_rcpf(e + 1.0f);
}

// Decomposition (changed from R5):
//   thread tid -> s = tid&7 (k-slice of 40), g = tid>>3 (neuron pair 2g, 2g+1)
//   K-reduction is IN-WAVE (shfl over lane bits 0..2) -> no part[] LDS round
//   trip, no reduce phase, ONE barrier per step.
// Weights are loaded via asm volatile global_load_dwordx4: the register
// allocator cannot rematerialize an asm def, so the 80 weight floats/lane
// MUST stay resident (R5 evidence: plain loads at VGPR_Count=60 were being
// re-fetched from L1/L2 every one of the 2048 iterations).
__global__
__attribute__((amdgpu_flat_work_group_size(NTHR, NTHR), amdgpu_waves_per_eu(4, 4)))
void rnn_kernel(const float* __restrict__ x,    // (T, B, F)
                const float* __restrict__ W0,   // (H, F+H) row-major
                const float* __restrict__ b0,   // (H)
                const float* __restrict__ Wfc,  // (1, H)
                const float* __restrict__ bfc,  // (1)
                float* __restrict__ out)        // (B, T)
{
    const int b    = blockIdx.x;
    const int tid  = threadIdx.x;
    const int w    = tid >> 6;
    const int lane = tid & 63;
    const int s    = tid & 7;          // k-slice index
    const int g    = tid >> 3;         // neuron-pair group 0..127
    const int n0   = 2 * g;
    const int n1   = 2 * g + 1;
    const int kbase = KCH * s;         // float offset into augmented input

    __shared__ float a_buf[2][KAUG];      // double-buffered [x_t ; h] (2.5 KB)
    __shared__ float out_buf[T_STEPS];    // per-step outputs (8 KB)
    // Occupancy limiter: total LDS = 2560 + 8192 + 71424 = 82176 B > 81920 B
    // -> only 1 workgroup/CU fits -> compiler VGPR budget = 128/lane.
    __shared__ float lds_pad[17856];

    // keep lds_pad alive: branch never taken (grid is 256)
    if (blockIdx.x == 0xFFFFFFFFu) {
        ((volatile float*)lds_pad)[tid] = 1.0f;
    }

    // ---- asm-pinned weight registers: w0r/w1r = rows n0/n1, cols [kbase,kbase+40)
    f32x4 w0r[NC], w1r[NC];
    {
        const float* p0 = W0 + n0 * KAUG + kbase;
        const float* p1 = W0 + n1 * KAUG + kbase;
#pragma unroll
        for (int c = 0; c < NC; ++c) {
            asm volatile("global_load_dwordx4 %0, %1, off offset:%2"
                         : "=v"(w0r[c]) : "v"(p0), "i"(16 * c));
            asm volatile("global_load_dwordx4 %0, %1, off offset:%2"
                         : "=v"(w1r[c]) : "v"(p1), "i"(16 * c));
        }
        asm volatile("s_waitcnt vmcnt(0)" ::: "memory");
        __builtin_amdgcn_sched_barrier(0);   // rule #18: no hoisting past the wait
    }

    const float b00 = b0[n0],  b01 = b0[n1];
    const float wf0 = Wfc[n0], wf1 = Wfc[n1];
    const float bfc_r = bfc[0];

    // prologue: a_buf[0] = [x_0 ; h0=0]; out_buf[t] = bfc
    if (tid < FEAT) a_buf[0][tid] = x[b * FEAT + tid];
    if (tid < HID)  a_buf[0][FEAT + tid] = 0.0f;
    out_buf[tid]        = bfc_r;
    out_buf[tid + NTHR] = bfc_r;
    __syncthreads();

    for (int t = 0; t < T_STEPS; ++t) {
        const int cur = t & 1;
        const int nxt = cur ^ 1;

        // prefetch x for step t+1, spread over all 16 waves (lanes 0..3 each)
        float xnext = 0.0f;
        const int xe = (w << 2) | (lane & 3);   // element 0..63
        if (lane < 4) {
            const int tn = (t + 1 < T_STEPS) ? (t + 1) : t;
            xnext = x[tn * (BATCH * FEAT) + b * FEAT + xe];
        }

        // ---- FMA phase: 80 fp32 FMAs/lane (2 neurons x 40 k), fed by
        // 10 ds_read_b128 with only 8 distinct addresses/wave (~2-way, free)
        float a0 = 0.f, a1 = 0.f, a2 = 0.f, a3 = 0.f;
        const f32x4* a4 = reinterpret_cast<const f32x4*>(&a_buf[cur][kbase]);
#pragma unroll
        for (int c = 0; c < NC; ++c) {
            const f32x4 av  = a4[c];
            const f32x4 w0v = w0r[c];
            const f32x4 w1v = w1r[c];
            a0 = fmaf(w0v.x, av.x, a0);
            a1 = fmaf(w1v.x, av.x, a1);
            a2 = fmaf(w0v.y, av.y, a2);
            a3 = fmaf(w1v.y, av.y, a3);
            a0 = fmaf(w0v.z, av.z, a0);
            a1 = fmaf(w1v.z, av.z, a1);
            a2 = fmaf(w0v.w, av.w, a2);
            a3 = fmaf(w1v.w, av.w, a3);
        }
        float r0 = a0 + a2;   // neuron n0 partial (this k-slice)
        float r1 = a1 + a3;   // neuron n1 partial

        // ---- in-wave K-reduction over the 8 k-slices (lane bits 0..2)
#pragma unroll
        for (int m = 1; m <= 4; m <<= 1) {
            r0 += __shfl_xor(r0, m, 64);
            r1 += __shfl_xor(r1, m, 64);
        }
        const float h0 = fast_tanh(r0 + b00);
        const float h1 = fast_tanh(r1 + b01);

        // h write: one lane per group (s==0) stores both neurons as float2
        if (s == 0) {
            *reinterpret_cast<float2*>(&a_buf[nxt][FEAT + n0]) =
                make_float2(h0, h1);
        }
        if (lane < 4) a_buf[nxt][xe] = xnext;

        // ---- fc1: p identical across the 8 s-lanes of a group, so reducing
        // over lane bits 3..5 (masks 8,16,32) yields the wave's 16-neuron dot
        float p = fmaf(wf0, h0, wf1 * h1);
#pragma unroll
        for (int m = 8; m <= 32; m <<= 1) p += __shfl_xor(p, m, 64);
        if (lane == 0) atomicAdd(&out_buf[t], p);

        __syncthreads();   // a_buf[nxt] + out_buf[t] settled; ONE barrier/step
    }

    // epilogue: coalesced float2 store of the block's 2048 outputs
    float2* o2 = reinterpret_cast<float2*>(out + b * T_STEPS);
    const float2* s2 = reinterpret_cast<const float2*>(out_buf);
    o2[tid] = s2[tid];
}

extern "C" void kernel_launch(void* const* d_in, const int* in_sizes, int n_in,
                              void* d_out, int out_size, void* d_ws, size_t ws_size,
                              hipStream_t stream) {
    const float* x   = (const float*)d_in[0];
    const float* W0  = (const float*)d_in[1];
    const float* b0  = (const float*)d_in[2];
    const float* Wfc = (const float*)d_in[3];
    const float* bfc = (const float*)d_in[4];
    // d_in[5] = feature_n == 0 -> no autoregressive tail
    float* out = (float*)d_out;

    rnn_kernel<<<dim3(BATCH), dim3(NTHR), 0, stream>>>(x, W0, b0, Wfc, bfc, out);
}

// Round 2
// 1672.816 us; speedup vs baseline: 1.3290x; 1.3290x over previous
//
#include <hip/hip_runtime.h>

// Problem constants: T=2048, B=256, F=64, H=256, O=1
#define T_STEPS 2048
#define BATCH   256
#define FEAT    64
#define HID     256
#define KAUG    320   // FEAT + HID
#define NW      8     // waves per block
#define NTHR    512   // 8 waves = 2 waves/SIMD
#define XTILE   16    // timesteps per x staging tile

typedef _Float16 half8 __attribute__((ext_vector_type(8)));
typedef float    f32x4 __attribute__((ext_vector_type(4)));
typedef float    f32x8 __attribute__((ext_vector_type(8)));

// fast tanh: tanh(z) = 1 - 2/(exp(2z)+1). Saturates correctly at +/-inf.
__device__ __forceinline__ float fast_tanh(float z) {
    float e = __expf(2.0f * z);
    return 1.0f - 2.0f * __builtin_amdgcn_rcpf(e + 1.0f);
}

// R2: move the per-step matvec onto the MFMA pipe (MfmaUtil was 0.0 while the
// VALU did 80K MACs/step). MFMA reads A/B operands from AGPRs natively on
// gfx950 (unified file), so the R1 failure mode (arch/acc split forcing
// v_accvgpr_read per weight use) cannot recur: wherever the allocator puts the
// 80 regs of packed-f16 B-fragments, the MFMA consumes them for free.
//
// Decomposition: 1 batch element/block (grid=256=CUs). 8 waves; wave w owns
// neurons [32w, 32w+32) = 2 N-tiles of mfma_f32_16x16x32_f16. K=320 = 10
// chunks. A = [x_t ; h] lives as f16 row-0 in LDS; all 16 lanes of a k-group
// read the same 16B (LDS broadcast). C rows 1..15 are duplicate garbage and
// are discarded (row-separable). A/B use the same k-mapping k=(l>>4)*8+e, so
// any k-permutation ambiguity in the frag spec cancels in the dot product.
__global__
__attribute__((amdgpu_flat_work_group_size(NTHR, NTHR), amdgpu_waves_per_eu(2, 2)))
void rnn_kernel(const float* __restrict__ x,    // (T, B, F)
                const float* __restrict__ W0,   // (H, F+H) row-major
                const float* __restrict__ b0,   // (H)
                const float* __restrict__ Wfc,  // (1, H)
                const float* __restrict__ bfc,  // (1)
                float* __restrict__ out)        // (B, T)
{
    const int b    = blockIdx.x;
    const int tid  = threadIdx.x;
    const int w    = tid >> 6;
    const int lane = tid & 63;
    const int l15  = lane & 15;   // row/col-within-tile index
    const int kg   = lane >> 4;   // k-group 0..3 (8 f16 each)

    __shared__ __align__(16) _Float16 h_buf[2][HID];             // 1 KB
    __shared__ __align__(16) _Float16 x_tile[2][XTILE][FEAT];    // 4 KB
    __shared__ __align__(16) float    out_buf[T_STEPS];          // 8 KB

    // ---- B-fragments: wave w, tile nt covers neurons (2w+nt)*16 + l15.
    // Lane l, chunk c holds W0[n][c*32 + kg*8 .. +7] as 8 f16 (4 regs).
    // 20 frags = 80 regs/lane; budget at 2 waves/EU = 256 -> no spill pressure.
    half8 bw[2][10];
#pragma unroll
    for (int nt = 0; nt < 2; ++nt) {
        const int n = (2 * w + nt) * 16 + l15;
        const float* wp = W0 + n * KAUG + kg * 8;
#pragma unroll
        for (int c = 0; c < 10; ++c) {
            const f32x8 v = *reinterpret_cast<const f32x8*>(wp + c * 32);
            bw[nt][c] = __builtin_convertvector(v, half8);
        }
    }

    const float b00 = b0[32 * w + l15];
    const float b01 = b0[32 * w + 16 + l15];
    const float wf0 = Wfc[32 * w + l15];
    const float wf1 = Wfc[32 * w + 16 + l15];
    const float bfc_r = bfc[0];

    // ---- prologue: h = 0, out_buf = bfc, stage x tile 0 (steps 0..15)
    if (tid < HID) { h_buf[0][tid] = (_Float16)0.f; h_buf[1][tid] = (_Float16)0.f; }
#pragma unroll
    for (int i = 0; i < 4; ++i) out_buf[tid + i * NTHR] = bfc_r;

    const int tr = tid >> 5;          // 0..15: timestep-row within tile
    const int f2 = (tid & 31) * 2;    // 0..62: feature pair
    {
        const float2 v = *reinterpret_cast<const float2*>(
            x + (size_t)tr * (BATCH * FEAT) + b * FEAT + f2);
        union { _Float16 h[2]; unsigned u; } pk;
        pk.h[0] = (_Float16)v.x; pk.h[1] = (_Float16)v.y;
        *reinterpret_cast<unsigned*>(&x_tile[0][tr][f2]) = pk.u;
    }
    __syncthreads();

    for (int t = 0; t < T_STEPS; ++t) {
        const int cur = t & 1;
        const int nxt = cur ^ 1;
        const int xb  = (t >> 4) & 1;

        // stage x tile for steps t+16..t+31 (16-step prefetch distance:
        // ~5000 cyc >> HBM latency; loads issued here, LDS-written below)
        const bool do_stage = ((t & 15) == 0) && (t + XTILE < T_STEPS);
        float2 xld;
        if (do_stage) {
            xld = *reinterpret_cast<const float2*>(
                x + (size_t)(t + XTILE + tr) * (BATCH * FEAT) + b * FEAT + f2);
        }

        // ---- MFMA phase: A-frag chunk c = 16B at (k-group kg), chunks 0-1
        // come from the x tile, 2-9 from h. 4 independent acc chains.
        const _Float16* xrow = &x_tile[xb][t & 15][kg * 8];
        const _Float16* hrow = &h_buf[cur][kg * 8];

        f32x4 acc0a = {0.f, 0.f, 0.f, 0.f}, acc0b = {0.f, 0.f, 0.f, 0.f};
        f32x4 acc1a = {0.f, 0.f, 0.f, 0.f}, acc1b = {0.f, 0.f, 0.f, 0.f};
#pragma unroll
        for (int c = 0; c < 2; ++c) {
            const half8 af = *reinterpret_cast<const half8*>(xrow + c * 32);
            if (c & 1) {
                acc0b = __builtin_amdgcn_mfma_f32_16x16x32_f16(af, bw[0][c], acc0b, 0, 0, 0);
                acc1b = __builtin_amdgcn_mfma_f32_16x16x32_f16(af, bw[1][c], acc1b, 0, 0, 0);
            } else {
                acc0a = __builtin_amdgcn_mfma_f32_16x16x32_f16(af, bw[0][c], acc0a, 0, 0, 0);
                acc1a = __builtin_amdgcn_mfma_f32_16x16x32_f16(af, bw[1][c], acc1a, 0, 0, 0);
            }
        }
#pragma unroll
        for (int c = 2; c < 10; ++c) {
            const half8 af = *reinterpret_cast<const half8*>(hrow + (c - 2) * 32);
            if (c & 1) {
                acc0b = __builtin_amdgcn_mfma_f32_16x16x32_f16(af, bw[0][c], acc0b, 0, 0, 0);
                acc1b = __builtin_amdgcn_mfma_f32_16x16x32_f16(af, bw[1][c], acc1b, 0, 0, 0);
            } else {
                acc0a = __builtin_amdgcn_mfma_f32_16x16x32_f16(af, bw[0][c], acc0a, 0, 0, 0);
                acc1a = __builtin_amdgcn_mfma_f32_16x16x32_f16(af, bw[1][c], acc1a, 0, 0, 0);
            }
        }

        // stage-write the prefetched x pair into the other tile buffer
        if (do_stage) {
            union { _Float16 h[2]; unsigned u; } pk;
            pk.h[0] = (_Float16)xld.x; pk.h[1] = (_Float16)xld.y;
            *reinterpret_cast<unsigned*>(&x_tile[xb ^ 1][tr][f2]) = pk.u;
        }

        // ---- epilogue: C/D row 0 = lanes 0..15, reg 0 (m89-verified layout)
        if (lane < 16) {
            const float h0 = fast_tanh(acc0a[0] + acc0b[0] + b00);
            const float h1 = fast_tanh(acc1a[0] + acc1b[0] + b01);
            h_buf[nxt][32 * w + l15]      = (_Float16)h0;
            h_buf[nxt][32 * w + 16 + l15] = (_Float16)h1;

            // fc1: reduce 32 neurons over lanes 0..15, one LDS atomic per wave
            float p = fmaf(wf0, h0, wf1 * h1);
#pragma unroll
            for (int m = 1; m <= 8; m <<= 1) p += __shfl_xor(p, m, 64);
            if (lane == 0) atomicAdd(&out_buf[t], p);
        }
        __syncthreads();   // h_buf[nxt], x_tile, out_buf[t] settled; 1 barrier/step
    }

    // ---- epilogue: coalesced float4 store of the block's 2048 outputs
    f32x4* o4 = reinterpret_cast<f32x4*>(out + b * T_STEPS);
    const f32x4* s4 = reinterpret_cast<const f32x4*>(out_buf);
    o4[tid] = s4[tid];
}

extern "C" void kernel_launch(void* const* d_in, const int* in_sizes, int n_in,
                              void* d_out, int out_size, void* d_ws, size_t ws_size,
                              hipStream_t stream) {
    const float* x   = (const float*)d_in[0];
    const float* W0  = (const float*)d_in[1];
    const float* b0  = (const float*)d_in[2];
    const float* Wfc = (const float*)d_in[3];
    const float* bfc = (const float*)d_in[4];
    // d_in[5] = feature_n == 0 -> no autoregressive tail
    float* out = (float*)d_out;

    rnn_kernel<<<dim3(BATCH), dim3(NTHR), 0, stream>>>(x, W0, b0, Wfc, bfc, out);
}